// Round 3
// baseline (257.635 us; speedup 1.0000x reference)
//
#include <hip/hip_runtime.h>
#include <hip/hip_bf16.h>
#include <cstdint>
#include <cstddef>

typedef __attribute__((ext_vector_type(8))) _Float16 half8;
typedef __attribute__((ext_vector_type(4))) float f32x4;
typedef __attribute__((ext_vector_type(8))) unsigned short ushort8v;
typedef __attribute__((ext_vector_type(4))) unsigned short ushort4v;

__device__ __forceinline__ unsigned short f2h_bits(float x) {
  _Float16 h = (_Float16)x;
  union { _Float16 h; unsigned short u; } cv; cv.h = h; return cv.u;
}

// ---------------- prep kernels ----------------

__global__ __launch_bounds__(256) void k_f32_to_f16(const float* __restrict__ src,
                                                    unsigned short* __restrict__ dst, int n4) {
  int i = blockIdx.x * 256 + threadIdx.x;
  if (i >= n4) return;
  float4 v = ((const float4*)src)[i];
  ushort4v o;
  o[0] = f2h_bits(v.x); o[1] = f2h_bits(v.y); o[2] = f2h_bits(v.z); o[3] = f2h_bits(v.w);
  ((ushort4v*)dst)[i] = o;
}

// W [Kd][N] fp32 (row-major) -> Wt rows [n][Kd] fp16
__global__ __launch_bounds__(256) void k_transpose_f16(const float* __restrict__ W,
                                                       unsigned short* __restrict__ Wt,
                                                       int Kd, int N) {
  int tid = blockIdx.x * 256 + threadIdx.x;
  int total = (Kd >> 3) * N;
  if (tid >= total) return;
  int kc = tid / N;
  int n  = tid - kc * N;
  int k0 = kc << 3;
  ushort8v o;
#pragma unroll
  for (int j = 0; j < 8; ++j) o[j] = f2h_bits(W[(size_t)(k0 + j) * N + n]);
  *(ushort8v*)(&Wt[(size_t)n * Kd + k0]) = o;
}

// Build unpacked head weight whd [2304][512] fp16 and bias bhd [2304] f32.
// rows 0..127: mu; 128..2175: tril unpacked (k*256+i*16+j, zero if j>i);
// 2176..2183: pi; 2184..2303: zero pad.
__global__ __launch_bounds__(256) void k_build_head(
    const float* __restrict__ Wmu, const float* __restrict__ Wt,
    const float* __restrict__ Wpi,
    const float* __restrict__ bmu, const float* __restrict__ bt,
    const float* __restrict__ bpi,
    unsigned short* __restrict__ whd, float* __restrict__ bhd)
{
  int tid = blockIdx.x * 256 + threadIdx.x;   // (r, d-chunk of 8): 2304*64
  if (tid >= 2304 * 64) return;
  int r  = tid >> 6;
  int d0 = (tid & 63) << 3;

  const float* src = nullptr; int stride = 0;
  if (r < 128) { src = Wmu + r; stride = 128; }
  else if (r < 2176) {
    int rU = r - 128, k = rU >> 8, i = (rU >> 4) & 15, j = rU & 15;
    if (j <= i) { src = Wt + k * 136 + ((i * (i + 1)) >> 1) + j; stride = 1088; }
  } else if (r < 2184) { src = Wpi + (r - 2176); stride = 8; }

  ushort8v o;
#pragma unroll
  for (int jj = 0; jj < 8; ++jj)
    o[jj] = src ? f2h_bits(src[(size_t)(d0 + jj) * stride]) : (unsigned short)0;
  *(ushort8v*)(&whd[(size_t)r * 512 + d0]) = o;

  if (d0 == 0) {
    float b = 0.f;
    if (r < 128) b = bmu[r];
    else if (r < 2176) {
      int rU = r - 128, k = rU >> 8, i = (rU >> 4) & 15, j = rU & 15;
      if (j <= i) b = bt[k * 136 + ((i * (i + 1)) >> 1) + j];
    } else if (r < 2184) b = bpi[r - 2176];
    bhd[r] = b;
  }
}

// ---------------- MFMA GEMM: BMxBN tile, BK=64, 8 waves, 2-phase dbuf ----------------
// A: [M][Kd] fp16.  Bt: [N][Kd] fp16.
// Wave (wm,wn) = (wid>>2, wid&3) owns a (BM/2)x(BN/4) output sub-tile.
// EPI 0: Hout[row*N+col] = fp16(relu(acc+bias[col]))
// EPI 1: head epilogue (mu / tril-with-exp-diag / pi-softmax), bias = bhd

template<int BM, int BN, int EPI>
__global__ __launch_bounds__(512, 2) void k_gemm(
    const unsigned short* __restrict__ A,
    const unsigned short* __restrict__ Bt,
    int Kd, int N, int nMb,
    const float* __restrict__ bias,
    unsigned short* __restrict__ Hout,
    float* __restrict__ out_pi,
    float* __restrict__ out_mu,
    float* __restrict__ out_tril)
{
  constexpr int BK    = 64;
  constexpr int M_rep = BM / 32;   // fragments per wave in M (BM/2 rows / 16)
  constexpr int N_rep = BN / 64;   // fragments per wave in N (BN/4 cols / 16)
  constexpr int ACH   = BM / 64;   // 16B chunks per thread for A staging
  constexpr int BCH   = BN / 64;

  __shared__ unsigned short Alds[2][BM * BK];
  __shared__ unsigned short Blds[2][BN * BK];

  const int tid  = threadIdx.x;
  const int lane = tid & 63;
  const int wid  = tid >> 6;     // 0..7
  const int wm   = wid >> 2;     // 0..1
  const int wn   = wid & 3;      // 0..3
  const int l15  = lane & 15;
  const int lk   = lane >> 4;    // k-group 0..3

  // bijective XCD-aware swizzle (all launches have gridDim.x % 8 == 0)
  const int cpx = gridDim.x >> 3;
  const int bid = blockIdx.x;
  const int swz = (bid & 7) * cpx + (bid >> 3);
  const int bm  = (swz % nMb) * BM;
  const int bn  = (swz / nMb) * BN;

  const unsigned short* aBase = A  + (size_t)bm * Kd;
  const unsigned short* bBase = Bt + (size_t)bn * Kd;

  f32x4 acc[M_rep][N_rep] = {};

  auto stage = [&](int bb, int k0) {
#pragma unroll
    for (int i = 0; i < ACH; ++i) {
      const int c   = tid + (i << 9);        // 16B chunk id; row = c>>3
      const int row = c >> 3;
      const int col = (c & 7) << 3;
      __builtin_amdgcn_global_load_lds(
          (const __attribute__((address_space(1))) void*)(aBase + (size_t)row * Kd + k0 + col),
          (__attribute__((address_space(3))) void*)(&Alds[bb][(size_t)c << 3]),
          16, 0, 0);
    }
#pragma unroll
    for (int i = 0; i < BCH; ++i) {
      const int c   = tid + (i << 9);
      const int row = c >> 3;
      const int col = (c & 7) << 3;
      __builtin_amdgcn_global_load_lds(
          (const __attribute__((address_space(1))) void*)(bBase + (size_t)row * Kd + k0 + col),
          (__attribute__((address_space(3))) void*)(&Blds[bb][(size_t)c << 3]),
          16, 0, 0);
    }
  };

  const int nk = Kd >> 6;
  stage(0, 0);
  __syncthreads();
  int cur = 0;
  for (int kt = 0; kt < nk; ++kt) {
    if (kt + 1 < nk) stage(cur ^ 1, (kt + 1) << 6);   // prefetch overlaps MFMA below

    const unsigned short* al = &Alds[cur][(size_t)(wm * (BM / 2) + l15) * BK + (lk << 3)];
    const unsigned short* bl = &Blds[cur][(size_t)(wn * (BN / 4) + l15) * BK + (lk << 3)];
#pragma unroll
    for (int kk = 0; kk < 2; ++kk) {
      half8 af[M_rep], bfr[N_rep];
#pragma unroll
      for (int m = 0; m < M_rep; ++m) af[m]  = *(const half8*)(al + m * 16 * BK + kk * 32);
#pragma unroll
      for (int n = 0; n < N_rep; ++n) bfr[n] = *(const half8*)(bl + n * 16 * BK + kk * 32);
#pragma unroll
      for (int m = 0; m < M_rep; ++m)
#pragma unroll
        for (int n = 0; n < N_rep; ++n)
          acc[m][n] = __builtin_amdgcn_mfma_f32_16x16x32_f16(af[m], bfr[n], acc[m][n], 0, 0, 0);
    }

    __syncthreads();   // drains prefetch vmcnt + protects LDS reuse
    cur ^= 1;
  }

  // epilogue: row = bm + wm*(BM/2) + m*16 + lk*4 + r ; col = bn + wn*(BN/4) + n*16 + l15
  const int orow0 = bm + wm * (BM / 2) + (lk << 2);
#pragma unroll
  for (int m = 0; m < M_rep; ++m) {
#pragma unroll
    for (int n = 0; n < N_rep; ++n) {
      const int col = bn + wn * (BN / 4) + (n << 4) + l15;
#pragma unroll
      for (int r = 0; r < 4; ++r) {
        const int row = orow0 + (m << 4) + r;
        if (EPI == 0) {
          float v = acc[m][n][r] + bias[col];
          v = v > 0.f ? v : 0.f;
          Hout[(size_t)row * N + col] = f2h_bits(v);
        } else {
          float v = acc[m][n][r] + bias[col];
          if (col < 128) {
            out_mu[(size_t)row * 128 + col] = v;
          } else if (col < 2176) {
            const int cc = col - 128;
            if (((cc >> 4) & 15) == (cc & 15)) v = expf(v);   // diagonal
            out_tril[(size_t)row * 2048 + cc] = v;            // zeros for j>i fall out
          } else if (col < 2184) {
            float mx = v;
#pragma unroll
            for (int s = 1; s < 8; s <<= 1) mx = fmaxf(mx, __shfl_xor(mx, s));
            float e = expf(v - mx);
            float sm = e;
#pragma unroll
            for (int s = 1; s < 8; s <<= 1) sm += __shfl_xor(sm, s);
            out_pi[((size_t)row << 3) + (col - 2176)] = e / sm;
          }
          // col >= 2184: padding, discard
        }
      }
    }
  }
}

// ---------------- launch ----------------

extern "C" void kernel_launch(void* const* d_in, const int* in_sizes, int n_in,
                              void* d_out, int out_size, void* d_ws, size_t ws_size,
                              hipStream_t stream)
{
  const float* x   = (const float*)d_in[0];
  const float* W0  = (const float*)d_in[1];
  const float* b0  = (const float*)d_in[2];
  const float* W1  = (const float*)d_in[3];
  const float* b1  = (const float*)d_in[4];
  const float* W2  = (const float*)d_in[5];
  const float* b2  = (const float*)d_in[6];
  const float* Wpi = (const float*)d_in[7];
  const float* bpi = (const float*)d_in[8];
  const float* Wmu = (const float*)d_in[9];
  const float* bmu = (const float*)d_in[10];
  const float* Wt  = (const float*)d_in[11];
  const float* bt  = (const float*)d_in[12];

  char* ws = (char*)d_ws;
  unsigned short* xh  = (unsigned short*)(ws);             //  8,388,608 B
  unsigned short* h0  = (unsigned short*)(ws + 8388608);   // 33,554,432 B
  unsigned short* h1  = (unsigned short*)(ws + 41943040);  // 33,554,432 B
  unsigned short* h2  = (unsigned short*)(ws + 8388608);   // 16,777,216 B (aliases h0 — dead by then)
  unsigned short* w0b = (unsigned short*)(ws + 75497472);  //    524,288 B [1024][256]
  unsigned short* w1b = (unsigned short*)(ws + 76021760);  //  2,097,152 B [1024][1024]
  unsigned short* w2b = (unsigned short*)(ws + 78118912);  //  1,048,576 B [512][1024]
  unsigned short* whd = (unsigned short*)(ws + 79167488);  //  2,359,296 B [2304][512]
  float*          bhd = (float*)         (ws + 81526784);  //      9,216 B [2304]

  float* out_pi   = (float*)d_out;                // 131072
  float* out_mu   = (float*)d_out + 131072;       // 2097152
  float* out_tril = (float*)d_out + 2228224;      // 33554432

  // prep
  k_f32_to_f16<<<4096, 256, 0, stream>>>(x, xh, 1048576);
  k_transpose_f16<<<128, 256, 0, stream>>>(W0, w0b, 256, 1024);
  k_transpose_f16<<<512, 256, 0, stream>>>(W1, w1b, 1024, 1024);
  k_transpose_f16<<<256, 256, 0, stream>>>(W2, w2b, 1024, 512);
  k_build_head<<<576, 256, 0, stream>>>(Wmu, Wt, Wpi, bmu, bt, bpi, whd, bhd);

  // trunk GEMMs (M=16384)
  k_gemm<256, 256, 0><<<256, 512, 0, stream>>>(xh, w0b, 256, 1024, 64, b0, h0,
                                               nullptr, nullptr, nullptr);
  k_gemm<256, 256, 0><<<256, 512, 0, stream>>>(h0, w1b, 1024, 1024, 64, b1, h1,
                                               nullptr, nullptr, nullptr);
  k_gemm<128, 256, 0><<<256, 512, 0, stream>>>(h1, w2b, 1024, 512, 128, b2, h2,
                                               nullptr, nullptr, nullptr);
  // heads: mu + tril + pi in one GEMM (N = 2304: 128 mu | 2048 tril | 8 pi | 120 pad)
  k_gemm<256, 256, 1><<<576, 512, 0, stream>>>(h2, whd, 512, 2304, 64, bhd, nullptr,
                                               out_pi, out_mu, out_tril);
}

// Round 4
// 242.758 us; speedup vs baseline: 1.0613x; 1.0613x over previous
//
#include <hip/hip_runtime.h>
#include <hip/hip_bf16.h>
#include <cstdint>
#include <cstddef>

typedef __attribute__((ext_vector_type(8))) _Float16 half8;
typedef __attribute__((ext_vector_type(4))) float f32x4;
typedef __attribute__((ext_vector_type(8))) unsigned short ushort8v;
typedef __attribute__((ext_vector_type(4))) unsigned short ushort4v;

__device__ __forceinline__ unsigned short f2h_bits(float x) {
  _Float16 h = (_Float16)x;
  union { _Float16 h; unsigned short u; } cv; cv.h = h; return cv.u;
}

__device__ __forceinline__ void barrier_raw() {
  asm volatile("" ::: "memory");
  __builtin_amdgcn_s_barrier();
  asm volatile("" ::: "memory");
}
__device__ __forceinline__ void lgkm0() {
  asm volatile("s_waitcnt lgkmcnt(0)" ::: "memory");
}
template<int N> __device__ __forceinline__ void vmw() {
  static_assert(N == 0 || N == 3 || N == 4, "unsupported vmcnt");
  if constexpr (N == 0) asm volatile("s_waitcnt vmcnt(0)" ::: "memory");
  if constexpr (N == 3) asm volatile("s_waitcnt vmcnt(3)" ::: "memory");
  if constexpr (N == 4) asm volatile("s_waitcnt vmcnt(4)" ::: "memory");
}

// ---------------- prep kernels (unchanged from round 2, verified) ----------------

__global__ __launch_bounds__(256) void k_f32_to_f16(const float* __restrict__ src,
                                                    unsigned short* __restrict__ dst, int n4) {
  int i = blockIdx.x * 256 + threadIdx.x;
  if (i >= n4) return;
  float4 v = ((const float4*)src)[i];
  ushort4v o;
  o[0] = f2h_bits(v.x); o[1] = f2h_bits(v.y); o[2] = f2h_bits(v.z); o[3] = f2h_bits(v.w);
  ((ushort4v*)dst)[i] = o;
}

__global__ __launch_bounds__(256) void k_transpose_f16(const float* __restrict__ W,
                                                       unsigned short* __restrict__ Wt,
                                                       int Kd, int N) {
  int tid = blockIdx.x * 256 + threadIdx.x;
  int total = (Kd >> 3) * N;
  if (tid >= total) return;
  int kc = tid / N;
  int n  = tid - kc * N;
  int k0 = kc << 3;
  ushort8v o;
#pragma unroll
  for (int j = 0; j < 8; ++j) o[j] = f2h_bits(W[(size_t)(k0 + j) * N + n]);
  *(ushort8v*)(&Wt[(size_t)n * Kd + k0]) = o;
}

__global__ __launch_bounds__(256) void k_build_head(
    const float* __restrict__ Wmu, const float* __restrict__ Wt,
    const float* __restrict__ Wpi,
    const float* __restrict__ bmu, const float* __restrict__ bt,
    const float* __restrict__ bpi,
    unsigned short* __restrict__ whd, float* __restrict__ bhd)
{
  int tid = blockIdx.x * 256 + threadIdx.x;
  if (tid >= 2304 * 64) return;
  int r  = tid >> 6;
  int d0 = (tid & 63) << 3;

  const float* src = nullptr; int stride = 0;
  if (r < 128) { src = Wmu + r; stride = 128; }
  else if (r < 2176) {
    int rU = r - 128, k = rU >> 8, i = (rU >> 4) & 15, j = rU & 15;
    if (j <= i) { src = Wt + k * 136 + ((i * (i + 1)) >> 1) + j; stride = 1088; }
  } else if (r < 2184) { src = Wpi + (r - 2176); stride = 8; }

  ushort8v o;
#pragma unroll
  for (int jj = 0; jj < 8; ++jj)
    o[jj] = src ? f2h_bits(src[(size_t)(d0 + jj) * stride]) : (unsigned short)0;
  *(ushort8v*)(&whd[(size_t)r * 512 + d0]) = o;

  if (d0 == 0) {
    float b = 0.f;
    if (r < 128) b = bmu[r];
    else if (r < 2176) {
      int rU = r - 128, k = rU >> 8, i = (rU >> 4) & 15, j = rU & 15;
      if (j <= i) b = bt[k * 136 + ((i * (i + 1)) >> 1) + j];
    } else if (r < 2184) b = bpi[r - 2176];
    bhd[r] = b;
  }
}

// -------- MFMA GEMM: BMxBN tile, BK=64, 8 waves, 8-phase counted-vmcnt pipeline --------
// LDS per buffer: A split by K-half into [2][BM][32], B into [2][BN][32].
// XOR swizzle (T2, both-sides per rule 21): logical chunk (row,cl) stored at chunk
// cl ^ ((row>>1)&3); stage pre-swizzles the GLOBAL source, LDS dest stays linear.
// Schedule per K-tile t (4 phases): P1(kk0,nh0) stages A-kh0 of t+1; P2(kk0,nh1)
// stages B-kh0, then vmcnt(WN) [forces t-1's A-kh1/B-kh1 for P3/P4]; P3(kk1,nh0)
// stages A-kh1; P4(kk1,nh1) stages B-kh1, then vmcnt(WN) [forces t's A-kh0/B-kh0
// for next tile's P1/P2]. Raw s_barrier only — never __syncthreads (vmcnt(0) drain).

template<int NH, int M_rep>
__device__ __forceinline__ void mfma_phase(const half8* af, const half8* bf,
                                           f32x4 (*acc)[4]) {
  __builtin_amdgcn_s_setprio(1);
#pragma unroll
  for (int m = 0; m < M_rep; ++m) {
    acc[m][NH * 2 + 0] = __builtin_amdgcn_mfma_f32_16x16x32_f16(af[m], bf[0], acc[m][NH * 2 + 0], 0, 0, 0);
    acc[m][NH * 2 + 1] = __builtin_amdgcn_mfma_f32_16x16x32_f16(af[m], bf[1], acc[m][NH * 2 + 1], 0, 0, 0);
  }
  __builtin_amdgcn_s_setprio(0);
}

template<int BM, int BN, int EPI>
__global__ __launch_bounds__(512) void k_gemm8p(
    const unsigned short* __restrict__ A,
    const unsigned short* __restrict__ Bt,
    int Kd, int N, int nMb,
    const float* __restrict__ bias,
    unsigned short* __restrict__ Hout,
    float* __restrict__ out_pi,
    float* __restrict__ out_mu,
    float* __restrict__ out_tril)
{
  constexpr int M_rep = BM / 32;     // A-frags per wave (8 or 4)
  constexpr int A_LD  = BM / 128;    // global_load_lds per thread per A half-stage
  constexpr int B_LD  = BN / 128;
  constexpr int WN    = A_LD + B_LD; // steady-state vmcnt

  __shared__ unsigned short Ald[2][2][BM * 32];
  __shared__ unsigned short Bld[2][2][BN * 32];

  const int tid  = threadIdx.x;
  const int lane = tid & 63;
  const int wid  = tid >> 6;
  const int wm   = wid >> 2;
  const int wn   = wid & 3;
  const int l15  = lane & 15;
  const int lk   = lane >> 4;

  // bijective XCD swizzle (gridDim.x % 8 == 0 for all launches)
  const int cpx = gridDim.x >> 3;
  const int bid = blockIdx.x;
  const int swz = (bid & 7) * cpx + (bid >> 3);
  const int bm  = (swz % nMb) * BM;
  const int bn  = (swz / nMb) * BN;

  const unsigned short* aBase = A  + (size_t)bm * Kd;
  const unsigned short* bBase = Bt + (size_t)bn * Kd;

  f32x4 acc[M_rep][4] = {};

  // read-side swizzled chunk offset (elems); independent of m/n/kk (proof: row =
  // even_base + l15, so (row>>1)&3 = (base/2 + (l15>>1)) & 3, base/2 % 4 == 0)
  const int xo   = ((lk ^ ((l15 >> 1) & 3)) << 3);
  const int rowA = wm * (BM / 2) + l15;
  const int colB = wn * 64 + l15;

  auto stageA = [&](int bb, int h, int k0) {
#pragma unroll
    for (int i = 0; i < A_LD; ++i) {
      const int cbase = (wid << 6) + (i << 9);   // wave-uniform chunk base
      const int c_    = cbase + lane;
      const int row   = c_ >> 2;
      const int sc    = (((c_ & 3) ^ ((c_ >> 3) & 3)) << 3);  // pre-swizzled source
      __builtin_amdgcn_global_load_lds(
          (const __attribute__((address_space(1))) void*)(aBase + (size_t)row * Kd + k0 + h * 32 + sc),
          (__attribute__((address_space(3))) void*)(&Ald[bb][h][(size_t)cbase << 3]),
          16, 0, 0);
    }
  };
  auto stageB = [&](int bb, int h, int k0) {
#pragma unroll
    for (int i = 0; i < B_LD; ++i) {
      const int cbase = (wid << 6) + (i << 9);
      const int c_    = cbase + lane;
      const int row   = c_ >> 2;
      const int sc    = (((c_ & 3) ^ ((c_ >> 3) & 3)) << 3);
      __builtin_amdgcn_global_load_lds(
          (const __attribute__((address_space(1))) void*)(bBase + (size_t)row * Kd + k0 + h * 32 + sc),
          (__attribute__((address_space(3))) void*)(&Bld[bb][h][(size_t)cbase << 3]),
          16, 0, 0);
    }
  };

#define RD_A(kk)                                                                 \
  {                                                                              \
    _Pragma("unroll")                                                            \
    for (int m = 0; m < M_rep; ++m)                                              \
      af[m] = *(const half8*)&Ald[cur][kk][(size_t)(rowA + m * 16) * 32 + xo];   \
  }
#define RD_B(kk, nh)                                                             \
  {                                                                              \
    _Pragma("unroll")                                                            \
    for (int n2 = 0; n2 < 2; ++n2)                                               \
      bf[n2] = *(const half8*)&Bld[cur][kk][(size_t)(colB + ((nh) * 2 + n2) * 16) * 32 + xo]; \
  }

  const int nk = Kd >> 6;
  // prologue: tile 0 -> buf 0, issue order A-kh0, B-kh0, A-kh1, B-kh1
  stageA(0, 0, 0); stageB(0, 0, 0); stageA(0, 1, 0); stageB(0, 1, 0);
  vmw<WN>();              // forces A-kh0 + B-kh0; leaves kh1 pair in flight
  barrier_raw();

  int cur = 0;
  for (int kt = 0; kt < nk; ++kt) {
    const bool pre = (kt + 1 < nk);
    const int  k0n = (kt + 1) << 6;
    half8 af[M_rep], bf[2];

    // ---- P1 (kk0, nh0)
    RD_A(0); RD_B(0, 0);
    if (pre) stageA(cur ^ 1, 0, k0n);
    barrier_raw(); lgkm0();
    mfma_phase<0, M_rep>(af, bf, acc);
    barrier_raw();

    // ---- P2 (kk0, nh1)
    RD_B(0, 1);
    if (pre) stageB(cur ^ 1, 0, k0n);
    barrier_raw(); lgkm0();
    mfma_phase<1, M_rep>(af, bf, acc);
    if (pre) vmw<WN>(); else vmw<0>();   // forces prev tile's kh1 pair (read in P3/P4)
    barrier_raw();

    // ---- P3 (kk1, nh0)
    RD_A(1); RD_B(1, 0);
    if (pre) stageA(cur ^ 1, 1, k0n);
    barrier_raw(); lgkm0();
    mfma_phase<0, M_rep>(af, bf, acc);
    barrier_raw();

    // ---- P4 (kk1, nh1)
    RD_B(1, 1);
    if (pre) stageB(cur ^ 1, 1, k0n);
    barrier_raw(); lgkm0();
    mfma_phase<1, M_rep>(af, bf, acc);
    if (pre) vmw<WN>();                  // forces this tile's kh0 pair (next P1/P2)
    barrier_raw();

    cur ^= 1;
  }
#undef RD_A
#undef RD_B

  // epilogue: row = bm + wm*(BM/2) + m*16 + lk*4 + r ; col = bn + wn*64 + n*16 + l15
  const int orow0 = bm + wm * (BM / 2) + (lk << 2);
#pragma unroll
  for (int m = 0; m < M_rep; ++m) {
#pragma unroll
    for (int n = 0; n < 4; ++n) {
      const int col = bn + wn * 64 + (n << 4) + l15;
#pragma unroll
      for (int r = 0; r < 4; ++r) {
        const int row = orow0 + (m << 4) + r;
        if (EPI == 0) {
          float v = acc[m][n][r] + bias[col];
          v = v > 0.f ? v : 0.f;
          Hout[(size_t)row * N + col] = f2h_bits(v);
        } else {
          float v = acc[m][n][r] + bias[col];
          if (col < 128) {
            out_mu[(size_t)row * 128 + col] = v;
          } else if (col < 2176) {
            const int cc = col - 128;
            if (((cc >> 4) & 15) == (cc & 15)) v = expf(v);   // diagonal
            out_tril[(size_t)row * 2048 + cc] = v;            // zero rows give j>i zeros
          } else if (col < 2184) {
            float mx = v;
#pragma unroll
            for (int s = 1; s < 8; s <<= 1) mx = fmaxf(mx, __shfl_xor(mx, s));
            float e = expf(v - mx);
            float sm = e;
#pragma unroll
            for (int s = 1; s < 8; s <<= 1) sm += __shfl_xor(sm, s);
            out_pi[((size_t)row << 3) + (col - 2176)] = e / sm;
          }
        }
      }
    }
  }
}

// ---------------- launch ----------------

extern "C" void kernel_launch(void* const* d_in, const int* in_sizes, int n_in,
                              void* d_out, int out_size, void* d_ws, size_t ws_size,
                              hipStream_t stream)
{
  const float* x   = (const float*)d_in[0];
  const float* W0  = (const float*)d_in[1];
  const float* b0  = (const float*)d_in[2];
  const float* W1  = (const float*)d_in[3];
  const float* b1  = (const float*)d_in[4];
  const float* W2  = (const float*)d_in[5];
  const float* b2  = (const float*)d_in[6];
  const float* Wpi = (const float*)d_in[7];
  const float* bpi = (const float*)d_in[8];
  const float* Wmu = (const float*)d_in[9];
  const float* bmu = (const float*)d_in[10];
  const float* Wt  = (const float*)d_in[11];
  const float* bt  = (const float*)d_in[12];

  char* ws = (char*)d_ws;
  unsigned short* xh  = (unsigned short*)(ws);             //  8,388,608 B
  unsigned short* h0  = (unsigned short*)(ws + 8388608);   // 33,554,432 B
  unsigned short* h1  = (unsigned short*)(ws + 41943040);  // 33,554,432 B
  unsigned short* h2  = (unsigned short*)(ws + 8388608);   // 16,777,216 B (aliases h0 — dead by then)
  unsigned short* w0b = (unsigned short*)(ws + 75497472);  //    524,288 B [1024][256]
  unsigned short* w1b = (unsigned short*)(ws + 76021760);  //  2,097,152 B [1024][1024]
  unsigned short* w2b = (unsigned short*)(ws + 78118912);  //  1,048,576 B [512][1024]
  unsigned short* whd = (unsigned short*)(ws + 79167488);  //  2,359,296 B [2304][512]
  float*          bhd = (float*)         (ws + 81526784);  //      9,216 B [2304]

  float* out_pi   = (float*)d_out;                // 131072
  float* out_mu   = (float*)d_out + 131072;       // 2097152
  float* out_tril = (float*)d_out + 2228224;      // 33554432

  // prep
  k_f32_to_f16<<<4096, 256, 0, stream>>>(x, xh, 1048576);
  k_transpose_f16<<<128, 256, 0, stream>>>(W0, w0b, 256, 1024);
  k_transpose_f16<<<512, 256, 0, stream>>>(W1, w1b, 1024, 1024);
  k_transpose_f16<<<256, 256, 0, stream>>>(W2, w2b, 1024, 512);
  k_build_head<<<576, 256, 0, stream>>>(Wmu, Wt, Wpi, bmu, bt, bpi, whd, bhd);

  // trunk GEMMs (M=16384)
  k_gemm8p<256, 256, 0><<<256, 512, 0, stream>>>(xh, w0b, 256, 1024, 64, b0, h0,
                                                 nullptr, nullptr, nullptr);
  k_gemm8p<256, 256, 0><<<256, 512, 0, stream>>>(h0, w1b, 1024, 1024, 64, b1, h1,
                                                 nullptr, nullptr, nullptr);
  k_gemm8p<128, 256, 0><<<256, 512, 0, stream>>>(h1, w2b, 1024, 512, 128, b2, h2,
                                                 nullptr, nullptr, nullptr);
  // heads: mu + tril + pi in one GEMM (N = 2304: 128 mu | 2048 tril | 8 pi | 120 pad)
  k_gemm8p<256, 256, 1><<<576, 512, 0, stream>>>(h2, whd, 512, 2304, 64, bhd, nullptr,
                                                 out_pi, out_mu, out_tril);
}

// Round 5
// 185.565 us; speedup vs baseline: 1.3884x; 1.3082x over previous
//
#include <hip/hip_runtime.h>
#include <hip/hip_bf16.h>
#include <cstdint>
#include <cstddef>

typedef __attribute__((ext_vector_type(8))) _Float16 half8;
typedef __attribute__((ext_vector_type(4))) float f32x4;
typedef __attribute__((ext_vector_type(8))) unsigned short ushort8v;
typedef __attribute__((ext_vector_type(4))) unsigned short ushort4v;

__device__ __forceinline__ unsigned short f2h_bits(float x) {
  _Float16 h = (_Float16)x;
  union { _Float16 h; unsigned short u; } cv; cv.h = h; return cv.u;
}

__device__ __forceinline__ void barrier_raw() {
  asm volatile("" ::: "memory");
  __builtin_amdgcn_s_barrier();
  asm volatile("" ::: "memory");
}
__device__ __forceinline__ void lgkm0() {
  asm volatile("s_waitcnt lgkmcnt(0)" ::: "memory");
}
template<int N> __device__ __forceinline__ void vmw() {
  static_assert(N == 0 || N == 3 || N == 4, "unsupported vmcnt");
  if constexpr (N == 0) asm volatile("s_waitcnt vmcnt(0)" ::: "memory");
  if constexpr (N == 3) asm volatile("s_waitcnt vmcnt(3)" ::: "memory");
  if constexpr (N == 4) asm volatile("s_waitcnt vmcnt(4)" ::: "memory");
}

// ---------------- prep kernels (verified rounds 1-4) ----------------

__global__ __launch_bounds__(256) void k_f32_to_f16(const float* __restrict__ src,
                                                    unsigned short* __restrict__ dst, int n4) {
  int i = blockIdx.x * 256 + threadIdx.x;
  if (i >= n4) return;
  float4 v = ((const float4*)src)[i];
  ushort4v o;
  o[0] = f2h_bits(v.x); o[1] = f2h_bits(v.y); o[2] = f2h_bits(v.z); o[3] = f2h_bits(v.w);
  ((ushort4v*)dst)[i] = o;
}

__global__ __launch_bounds__(256) void k_transpose_f16(const float* __restrict__ W,
                                                       unsigned short* __restrict__ Wt,
                                                       int Kd, int N) {
  int tid = blockIdx.x * 256 + threadIdx.x;
  int total = (Kd >> 3) * N;
  if (tid >= total) return;
  int kc = tid / N;
  int n  = tid - kc * N;
  int k0 = kc << 3;
  ushort8v o;
#pragma unroll
  for (int j = 0; j < 8; ++j) o[j] = f2h_bits(W[(size_t)(k0 + j) * N + n]);
  *(ushort8v*)(&Wt[(size_t)n * Kd + k0]) = o;
}

__global__ __launch_bounds__(256) void k_build_head(
    const float* __restrict__ Wmu, const float* __restrict__ Wt,
    const float* __restrict__ Wpi,
    const float* __restrict__ bmu, const float* __restrict__ bt,
    const float* __restrict__ bpi,
    unsigned short* __restrict__ whd, float* __restrict__ bhd)
{
  int tid = blockIdx.x * 256 + threadIdx.x;
  if (tid >= 2304 * 64) return;
  int r  = tid >> 6;
  int d0 = (tid & 63) << 3;

  const float* src = nullptr; int stride = 0;
  if (r < 128) { src = Wmu + r; stride = 128; }
  else if (r < 2176) {
    int rU = r - 128, k = rU >> 8, i = (rU >> 4) & 15, j = rU & 15;
    if (j <= i) { src = Wt + k * 136 + ((i * (i + 1)) >> 1) + j; stride = 1088; }
  } else if (r < 2184) { src = Wpi + (r - 2176); stride = 8; }

  ushort8v o;
#pragma unroll
  for (int jj = 0; jj < 8; ++jj)
    o[jj] = src ? f2h_bits(src[(size_t)(d0 + jj) * stride]) : (unsigned short)0;
  *(ushort8v*)(&whd[(size_t)r * 512 + d0]) = o;

  if (d0 == 0) {
    float b = 0.f;
    if (r < 128) b = bmu[r];
    else if (r < 2176) {
      int rU = r - 128, k = rU >> 8, i = (rU >> 4) & 15, j = rU & 15;
      if (j <= i) b = bt[k * 136 + ((i * (i + 1)) >> 1) + j];
    } else if (r < 2184) b = bpi[r - 2176];
    bhd[r] = b;
  }
}

// ---- shared epilogue helpers (swapped-operand layout: row=l15-side, col=lk*4+reg) ----

__device__ __forceinline__ void epi_relu_h(const f32x4& a, const float* bias, int col0,
                                           unsigned short* Hout, size_t row, int N) {
  float4 b4 = *(const float4*)&bias[col0];
  ushort4v o;
  float v0 = a[0] + b4.x; o[0] = f2h_bits(v0 > 0.f ? v0 : 0.f);
  float v1 = a[1] + b4.y; o[1] = f2h_bits(v1 > 0.f ? v1 : 0.f);
  float v2 = a[2] + b4.z; o[2] = f2h_bits(v2 > 0.f ? v2 : 0.f);
  float v3 = a[3] + b4.w; o[3] = f2h_bits(v3 > 0.f ? v3 : 0.f);
  *(ushort4v*)&Hout[row * N + col0] = o;
}

__device__ __forceinline__ void epi_head(const f32x4& a, const float* bias, int col0,
                                         size_t row, float* out_pi, float* out_mu,
                                         float* out_tril) {
  if (col0 >= 2184) return;   // pad
  float4 b4 = *(const float4*)&bias[col0];
  float v[4] = { a[0] + b4.x, a[1] + b4.y, a[2] + b4.z, a[3] + b4.w };
  if (col0 < 128) {
    *(float4*)&out_mu[row * 128 + col0] = make_float4(v[0], v[1], v[2], v[3]);
  } else if (col0 < 2176) {
    const int cc0 = col0 - 128;
    const int i   = (cc0 >> 4) & 15;
    const int j0  = cc0 & 15;
#pragma unroll
    for (int r = 0; r < 4; ++r) if (j0 + r == i) v[r] = expf(v[r]);
    *(float4*)&out_tril[row * 2048 + cc0] = make_float4(v[0], v[1], v[2], v[3]);
  } else {
    // pi: lanes lk=0 hold cols 2176-79, lk=1 hold 2180-83 for the same row (lane^16)
    float m4 = fmaxf(fmaxf(v[0], v[1]), fmaxf(v[2], v[3]));
    float mx = fmaxf(m4, __shfl_xor(m4, 16));
    float e[4], s4 = 0.f;
#pragma unroll
    for (int r = 0; r < 4; ++r) { e[r] = expf(v[r] - mx); s4 += e[r]; }
    float sm = s4 + __shfl_xor(s4, 16);
    *(float4*)&out_pi[row * 8 + (col0 - 2176)] =
        make_float4(e[0] / sm, e[1] / sm, e[2] / sm, e[3] / sm);
  }
}

// -------- 2-phase 128x128 GEMM: 4 waves, BK=32, dbuf (round-2 verified loop) --------
// A: [M][Kd] fp16.  Bt: [N][Kd] fp16.  SWAPPED mfma -> col-major-in-reg epilogue.
// Grid flat; bijective XCD swizzle, bn-minor (B panel stays in XCD L2).

template<int EPI>
__global__ __launch_bounds__(256) void k_gemm2p(
    const unsigned short* __restrict__ A,
    const unsigned short* __restrict__ Bt,
    int Kd, int N, int nNb,
    const float* __restrict__ bias,
    unsigned short* __restrict__ Hout,
    float* __restrict__ out_pi,
    float* __restrict__ out_mu,
    float* __restrict__ out_tril)
{
  __shared__ unsigned short Alds[2][128 * 32];
  __shared__ unsigned short Blds[2][128 * 32];

  const int tid  = threadIdx.x;
  const int lane = tid & 63;
  const int wv   = tid >> 6;
  const int wr   = wv >> 1;
  const int wc   = wv & 1;
  const int l15  = lane & 15;
  const int lk   = lane >> 4;

  const int cpx = gridDim.x >> 3;
  const int bid = blockIdx.x;
  const int swz = (bid & 7) * cpx + (bid >> 3);
  const int bm  = (swz / nNb) << 7;
  const int bn  = (swz % nNb) << 7;

  f32x4 acc[4][4] = {};

  const int srow = lane >> 2;
  const int scol = (lane & 3) << 3;

  const unsigned short* aBase = A  + (size_t)bm * Kd;
  const unsigned short* bBase = Bt + (size_t)bn * Kd;

  auto stage = [&](int bb, int k0) {
#pragma unroll
    for (int c = 0; c < 2; ++c) {
      const int chunk = (wv << 1) + c;
      const int row = (chunk << 4) + srow;
      __builtin_amdgcn_global_load_lds(
          (const __attribute__((address_space(1))) void*)(aBase + (size_t)row * Kd + k0 + scol),
          (__attribute__((address_space(3))) void*)(&Alds[bb][chunk << 9]),
          16, 0, 0);
      __builtin_amdgcn_global_load_lds(
          (const __attribute__((address_space(1))) void*)(bBase + (size_t)row * Kd + k0 + scol),
          (__attribute__((address_space(3))) void*)(&Blds[bb][chunk << 9]),
          16, 0, 0);
    }
  };

  const int nk = Kd >> 5;
  stage(0, 0);
  __syncthreads();
  int cur = 0;
  for (int kt = 0; kt < nk; ++kt) {
    if (kt + 1 < nk) stage(cur ^ 1, (kt + 1) << 5);

    const unsigned short* al = &Alds[cur][((wr << 6) + l15) * 32 + (lk << 3)];
    const unsigned short* bl = &Blds[cur][((wc << 6) + l15) * 32 + (lk << 3)];
    half8 af[4], bfr[4];
#pragma unroll
    for (int m = 0; m < 4; ++m) af[m]  = *(const half8*)(al + (m << 9));
#pragma unroll
    for (int n = 0; n < 4; ++n) bfr[n] = *(const half8*)(bl + (n << 9));
#pragma unroll
    for (int m = 0; m < 4; ++m)
#pragma unroll
      for (int n = 0; n < 4; ++n)   // SWAPPED operands: D[n-col-frag][m-row-frag]
        acc[m][n] = __builtin_amdgcn_mfma_f32_16x16x32_f16(bfr[n], af[m], acc[m][n], 0, 0, 0);

    __syncthreads();
    cur ^= 1;
  }

  // swapped layout: row = bm + wr*64 + m*16 + l15 ; col0 = bn + wc*64 + n*16 + lk*4
#pragma unroll
  for (int m = 0; m < 4; ++m) {
    const size_t row = bm + (wr << 6) + (m << 4) + l15;
#pragma unroll
    for (int n = 0; n < 4; ++n) {
      const int col0 = bn + (wc << 6) + (n << 4) + (lk << 2);
      if (EPI == 0) epi_relu_h(acc[m][n], bias, col0, Hout, row, N);
      else          epi_head(acc[m][n], bias, col0, row, out_pi, out_mu, out_tril);
    }
  }
}

// -------- 8-phase counted-vmcnt GEMM (round-4 verified loop), swapped epilogue --------

template<int NH, int M_rep>
__device__ __forceinline__ void mfma_phase(const half8* af, const half8* bf,
                                           f32x4 (*acc)[4]) {
  __builtin_amdgcn_s_setprio(1);
#pragma unroll
  for (int m = 0; m < M_rep; ++m) {   // SWAPPED operands
    acc[m][NH * 2 + 0] = __builtin_amdgcn_mfma_f32_16x16x32_f16(bf[0], af[m], acc[m][NH * 2 + 0], 0, 0, 0);
    acc[m][NH * 2 + 1] = __builtin_amdgcn_mfma_f32_16x16x32_f16(bf[1], af[m], acc[m][NH * 2 + 1], 0, 0, 0);
  }
  __builtin_amdgcn_s_setprio(0);
}

template<int BM, int BN>
__global__ __launch_bounds__(512) void k_gemm8p(
    const unsigned short* __restrict__ A,
    const unsigned short* __restrict__ Bt,
    int Kd, int N, int nNb,
    const float* __restrict__ bias,
    unsigned short* __restrict__ Hout)
{
  constexpr int M_rep = BM / 32;
  constexpr int A_LD  = BM / 128;
  constexpr int B_LD  = BN / 128;
  constexpr int WN    = A_LD + B_LD;

  __shared__ unsigned short Ald[2][2][BM * 32];
  __shared__ unsigned short Bld[2][2][BN * 32];

  const int tid  = threadIdx.x;
  const int lane = tid & 63;
  const int wid  = tid >> 6;
  const int wm   = wid >> 2;
  const int wn   = wid & 3;
  const int l15  = lane & 15;
  const int lk   = lane >> 4;

  const int cpx = gridDim.x >> 3;
  const int bid = blockIdx.x;
  const int swz = (bid & 7) * cpx + (bid >> 3);
  const int bm  = (swz / nNb) * BM;
  const int bn  = (swz % nNb) * BN;

  const unsigned short* aBase = A  + (size_t)bm * Kd;
  const unsigned short* bBase = Bt + (size_t)bn * Kd;

  f32x4 acc[M_rep][4] = {};

  const int xo   = ((lk ^ ((l15 >> 1) & 3)) << 3);
  const int rowA = wm * (BM / 2) + l15;
  const int colB = wn * 64 + l15;

  auto stageA = [&](int bb, int h, int k0) {
#pragma unroll
    for (int i = 0; i < A_LD; ++i) {
      const int cbase = (wid << 6) + (i << 9);
      const int c_    = cbase + lane;
      const int row   = c_ >> 2;
      const int sc    = (((c_ & 3) ^ ((c_ >> 3) & 3)) << 3);
      __builtin_amdgcn_global_load_lds(
          (const __attribute__((address_space(1))) void*)(aBase + (size_t)row * Kd + k0 + h * 32 + sc),
          (__attribute__((address_space(3))) void*)(&Ald[bb][h][(size_t)cbase << 3]),
          16, 0, 0);
    }
  };
  auto stageB = [&](int bb, int h, int k0) {
#pragma unroll
    for (int i = 0; i < B_LD; ++i) {
      const int cbase = (wid << 6) + (i << 9);
      const int c_    = cbase + lane;
      const int row   = c_ >> 2;
      const int sc    = (((c_ & 3) ^ ((c_ >> 3) & 3)) << 3);
      __builtin_amdgcn_global_load_lds(
          (const __attribute__((address_space(1))) void*)(bBase + (size_t)row * Kd + k0 + h * 32 + sc),
          (__attribute__((address_space(3))) void*)(&Bld[bb][h][(size_t)cbase << 3]),
          16, 0, 0);
    }
  };

#define RD_A(kk)                                                                 \
  {                                                                              \
    _Pragma("unroll")                                                            \
    for (int m = 0; m < M_rep; ++m)                                              \
      af[m] = *(const half8*)&Ald[cur][kk][(size_t)(rowA + m * 16) * 32 + xo];   \
  }
#define RD_B(kk, nh)                                                             \
  {                                                                              \
    _Pragma("unroll")                                                            \
    for (int n2 = 0; n2 < 2; ++n2)                                               \
      bf[n2] = *(const half8*)&Bld[cur][kk][(size_t)(colB + ((nh) * 2 + n2) * 16) * 32 + xo]; \
  }

  const int nk = Kd >> 6;
  stageA(0, 0, 0); stageB(0, 0, 0); stageA(0, 1, 0); stageB(0, 1, 0);
  vmw<WN>();
  barrier_raw();

  int cur = 0;
  for (int kt = 0; kt < nk; ++kt) {
    const bool pre = (kt + 1 < nk);
    const int  k0n = (kt + 1) << 6;
    half8 af[M_rep], bf[2];

    RD_A(0); RD_B(0, 0);
    if (pre) stageA(cur ^ 1, 0, k0n);
    barrier_raw(); lgkm0();
    mfma_phase<0, M_rep>(af, bf, acc);
    barrier_raw();

    RD_B(0, 1);
    if (pre) stageB(cur ^ 1, 0, k0n);
    barrier_raw(); lgkm0();
    mfma_phase<1, M_rep>(af, bf, acc);
    if (pre) vmw<WN>(); else vmw<0>();
    barrier_raw();

    RD_A(1); RD_B(1, 0);
    if (pre) stageA(cur ^ 1, 1, k0n);
    barrier_raw(); lgkm0();
    mfma_phase<0, M_rep>(af, bf, acc);
    barrier_raw();

    RD_B(1, 1);
    if (pre) stageB(cur ^ 1, 1, k0n);
    barrier_raw(); lgkm0();
    mfma_phase<1, M_rep>(af, bf, acc);
    if (pre) vmw<WN>();
    barrier_raw();

    cur ^= 1;
  }
#undef RD_A
#undef RD_B

  // swapped layout: row = bm + wm*(BM/2) + m*16 + l15 ; col0 = bn + wn*64 + n*16 + lk*4
#pragma unroll
  for (int m = 0; m < M_rep; ++m) {
    const size_t row = bm + wm * (BM / 2) + (m << 4) + l15;
#pragma unroll
    for (int n = 0; n < 4; ++n) {
      const int col0 = bn + wn * 64 + (n << 4) + (lk << 2);
      epi_relu_h(acc[m][n], bias, col0, Hout, row, N);
    }
  }
}

// ---------------- launch ----------------

extern "C" void kernel_launch(void* const* d_in, const int* in_sizes, int n_in,
                              void* d_out, int out_size, void* d_ws, size_t ws_size,
                              hipStream_t stream)
{
  const float* x   = (const float*)d_in[0];
  const float* W0  = (const float*)d_in[1];
  const float* b0  = (const float*)d_in[2];
  const float* W1  = (const float*)d_in[3];
  const float* b1  = (const float*)d_in[4];
  const float* W2  = (const float*)d_in[5];
  const float* b2  = (const float*)d_in[6];
  const float* Wpi = (const float*)d_in[7];
  const float* bpi = (const float*)d_in[8];
  const float* Wmu = (const float*)d_in[9];
  const float* bmu = (const float*)d_in[10];
  const float* Wt  = (const float*)d_in[11];
  const float* bt  = (const float*)d_in[12];

  char* ws = (char*)d_ws;
  unsigned short* xh  = (unsigned short*)(ws);             //  8,388,608 B
  unsigned short* h0  = (unsigned short*)(ws + 8388608);   // 33,554,432 B
  unsigned short* h1  = (unsigned short*)(ws + 41943040);  // 33,554,432 B
  unsigned short* h2  = (unsigned short*)(ws + 8388608);   // 16,777,216 B (aliases h0 — dead by then)
  unsigned short* w0b = (unsigned short*)(ws + 75497472);  //    524,288 B [1024][256]
  unsigned short* w1b = (unsigned short*)(ws + 76021760);  //  2,097,152 B [1024][1024]
  unsigned short* w2b = (unsigned short*)(ws + 78118912);  //  1,048,576 B [512][1024]
  unsigned short* whd = (unsigned short*)(ws + 79167488);  //  2,359,296 B [2304][512]
  float*          bhd = (float*)         (ws + 81526784);  //      9,216 B [2304]

  float* out_pi   = (float*)d_out;                // 131072
  float* out_mu   = (float*)d_out + 131072;       // 2097152
  float* out_tril = (float*)d_out + 2228224;      // 33554432

  // prep
  k_f32_to_f16<<<4096, 256, 0, stream>>>(x, xh, 1048576);
  k_transpose_f16<<<128, 256, 0, stream>>>(W0, w0b, 256, 1024);
  k_transpose_f16<<<512, 256, 0, stream>>>(W1, w1b, 1024, 1024);
  k_transpose_f16<<<256, 256, 0, stream>>>(W2, w2b, 1024, 512);
  k_build_head<<<576, 256, 0, stream>>>(Wmu, Wt, Wpi, bmu, bt, bpi, whd, bhd);

  // L0: short-K (256) -> 128^2 2-phase, 1024 blocks (~5/CU resident)
  k_gemm2p<0><<<1024, 256, 0, stream>>>(xh, w0b, 256, 1024, 8, b0, h0,
                                        nullptr, nullptr, nullptr);
  // L1/L2: K=1024 -> 256-class 8-phase, 256 blocks (1/CU exact)
  k_gemm8p<256, 256><<<256, 512, 0, stream>>>(h0, w1b, 1024, 1024, 4, b1, h1);
  k_gemm8p<128, 256><<<256, 512, 0, stream>>>(h1, w2b, 1024, 512, 2, b2, h2);
  // head: K=512 short, write-heavy -> 128^2 2-phase, 2304 blocks
  k_gemm2p<1><<<2304, 256, 0, stream>>>(h2, whd, 512, 2304, 18, bhd, nullptr,
                                        out_pi, out_mu, out_tril);
}